// Round 1
// baseline (284.835 us; speedup 1.0000x reference)
//
#include <hip/hip_runtime.h>

#define T_ROWS   1048576
#define F_COLS   64
#define K_FEATS  16
#define WINDOW   128
#define C_ROWS   512          // rows per block
#define NTHR     256
#define SUBS     (NTHR / K_FEATS)       // 16 thread-groups along rows
#define RPT      (C_ROWS / SUBS)        // 32 rows per Phase-A thread
#define F4       (F_COLS / 4)           // 16 float4 per row

__global__ __launch_bounds__(NTHR) void ma_fused_kernel(
    const float* __restrict__ inp,
    const int*   __restrict__ feats,
    float*       __restrict__ out)
{
    __shared__ float s_mean[C_ROWS][K_FEATS];   // 32 KB
    __shared__ int   s_feats[K_FEATS];
    __shared__ int   s_col2k[F_COLS];

    const int tid = threadIdx.x;
    const int r0  = blockIdx.x * C_ROWS;

    if (tid < F_COLS)  s_col2k[tid] = -1;
    if (tid < K_FEATS) s_feats[tid] = feats[tid];
    __syncthreads();
    if (tid < K_FEATS) s_col2k[s_feats[tid]] = tid;
    // col2k is only read after the post-Phase-A __syncthreads.

    // ---------------- Phase A: per-column sliding window sums ----------------
    {
        const int k   = tid & (K_FEATS - 1);
        const int sub = tid >> 4;                // 0..15
        const int t0  = r0 + sub * RPT;
        const int c   = s_feats[k];
        const float inv = 1.0f / (float)WINDOW;
        float S = 0.0f;

        if (r0 >= WINDOW) {
            // fast path: no boundary checks (all blocks except block 0)
            const float* p = inp + (t0 - WINDOW) * F_COLS + c;
            #pragma unroll 8
            for (int i = 0; i < WINDOW; ++i) S += p[i * F_COLS];

            const float* pe = inp + t0 * F_COLS + c;            // enter ptr
            const float* pl = inp + (t0 - WINDOW) * F_COLS + c; // leave ptr
            #pragma unroll 4
            for (int i = 0; i < RPT; ++i) {
                s_mean[t0 - r0 + i][k] = S * inv;
                float enter = pe[i * F_COLS];
                float leave = pl[i * F_COLS];
                S += enter - leave;
            }
        } else {
            // block 0: guarded
            for (int i = 0; i < WINDOW; ++i) {
                int t = t0 - WINDOW + i;
                if (t >= 0) S += inp[t * F_COLS + c];
            }
            for (int i = 0; i < RPT; ++i) {
                int t = t0 + i;
                s_mean[t - r0][k] = S * inv;
                float enter = inp[t * F_COLS + c];
                float leave = (t >= WINDOW) ? inp[(t - WINDOW) * F_COLS + c] : 0.0f;
                S += enter - leave;
            }
        }
    }
    __syncthreads();

    // ---------------- Phase B: coalesced float4 copy w/ substitution --------
    const float4* __restrict__ in4  = reinterpret_cast<const float4*>(inp);
    float4*       __restrict__ out4 = reinterpret_cast<float4*>(out);
    const int base = r0 * F4;

    if (r0 >= WINDOW) {
        #pragma unroll 4
        for (int f = tid; f < C_ROWS * F4; f += NTHR) {
            const int lt = f >> 4;         // local row
            const int j  = f & 15;         // float4 within row
            float4 v = in4[base + f];
            const int c0 = j << 2;
            int k0 = s_col2k[c0 + 0]; if (k0 >= 0) v.x = s_mean[lt][k0];
            int k1 = s_col2k[c0 + 1]; if (k1 >= 0) v.y = s_mean[lt][k1];
            int k2 = s_col2k[c0 + 2]; if (k2 >= 0) v.z = s_mean[lt][k2];
            int k3 = s_col2k[c0 + 3]; if (k3 >= 0) v.w = s_mean[lt][k3];
            out4[base + f] = v;
        }
    } else {
        for (int f = tid; f < C_ROWS * F4; f += NTHR) {
            const int lt = f >> 4;
            const int j  = f & 15;
            float4 v = in4[base + f];
            if (r0 + lt >= WINDOW) {
                const int c0 = j << 2;
                int k0 = s_col2k[c0 + 0]; if (k0 >= 0) v.x = s_mean[lt][k0];
                int k1 = s_col2k[c0 + 1]; if (k1 >= 0) v.y = s_mean[lt][k1];
                int k2 = s_col2k[c0 + 2]; if (k2 >= 0) v.z = s_mean[lt][k2];
                int k3 = s_col2k[c0 + 3]; if (k3 >= 0) v.w = s_mean[lt][k3];
            }
            out4[base + f] = v;
        }
    }
}

extern "C" void kernel_launch(void* const* d_in, const int* in_sizes, int n_in,
                              void* d_out, int out_size, void* d_ws, size_t ws_size,
                              hipStream_t stream) {
    const float* inp   = (const float*)d_in[0];
    const int*   feats = (const int*)d_in[1];
    float*       out   = (float*)d_out;

    dim3 grid(T_ROWS / C_ROWS);   // 2048 blocks
    dim3 block(NTHR);
    hipLaunchKernelGGL(ma_fused_kernel, grid, block, 0, stream,
                       inp, feats, out);
}

// Round 2
// 108.333 us; speedup vs baseline: 2.6292x; 2.6292x over previous
//
#include <hip/hip_runtime.h>

#define T_ROWS    1048576
#define F_COLS    64
#define K_FEATS   16
#define WINDOW    128
#define C_ROWS    512
#define NTHR      512
#define F4        16                  // float4 per row
#define HALO      128
#define TOT_ROWS  (C_ROWS + HALO)     // 640
#define SPAD      17                  // padded leading dim for s_cols
#define NCHUNK    (TOT_ROWS / 16)     // 40 chunks of 16 rows
#define NSUB      32                  // row sub-groups in phase A
#define RPT       (C_ROWS / NSUB)     // 16 rows per phase-A thread

__global__ __launch_bounds__(NTHR, 4) void ma_single_read_kernel(
    const float* __restrict__ inp,
    const int*   __restrict__ feats,
    float*       __restrict__ out)
{
    __shared__ float s_cols[TOT_ROWS][SPAD];   // 43.5 KB: halo+own feat cols, then means in-place
    __shared__ float s_ps[NCHUNK][K_FEATS];    // 2.5 KB: 16-row chunk sums

    const int tid   = threadIdx.x;
    const int r0    = blockIdx.x * C_ROWS;
    const bool first = (blockIdx.x == 0);

    const float4* __restrict__ in4 = reinterpret_cast<const float4*>(inp);
    const long base = (long)r0 * F4;

    // ---- issue ALL global loads first (20 x 16B per thread in flight) ----
    float4 f[16];                                  // block's own 512 rows
    #pragma unroll
    for (int j = 0; j < 16; ++j)
        f[j] = in4[base + tid + j * NTHR];

    float4 h[4];                                   // 128 halo rows
    if (!first) {
        const long hbase = (long)(r0 - HALO) * F4;
        #pragma unroll
        for (int m = 0; m < 4; ++m)
            h[m] = in4[hbase + tid + m * NTHR];
    }

    // ---- per-thread feat mapping: this thread always owns cols c0..c0+3 ----
    // (tid + j*512) & 15 == tid & 15, so the float4 slot is thread-invariant.
    const int c0 = (tid & 15) * 4;
    int k0 = -1, k1 = -1, k2 = -1, k3 = -1;
    #pragma unroll
    for (int i = 0; i < K_FEATS; ++i) {
        const int c = feats[i];                    // uniform -> scalar loads
        if (c == c0 + 0) k0 = i;
        if (c == c0 + 1) k1 = i;
        if (c == c0 + 2) k2 = i;
        if (c == c0 + 3) k3 = i;
    }
    const int rb = tid >> 4;                       // row-base 0..31

    // ---- extraction: scatter feat columns into s_cols ----
    if (!first) {
        #pragma unroll
        for (int m = 0; m < 4; ++m) {
            const int r = rb + m * 32;             // halo rows 0..127
            if (k0 >= 0) s_cols[r][k0] = h[m].x;
            if (k1 >= 0) s_cols[r][k1] = h[m].y;
            if (k2 >= 0) s_cols[r][k2] = h[m].z;
            if (k3 >= 0) s_cols[r][k3] = h[m].w;
        }
    } else {
        if (tid < HALO) {
            #pragma unroll
            for (int k = 0; k < K_FEATS; ++k) s_cols[tid][k] = 0.0f;
        }
    }
    #pragma unroll
    for (int j = 0; j < 16; ++j) {
        const int r = HALO + rb + j * 32;          // own rows 128..639
        if (k0 >= 0) s_cols[r][k0] = f[j].x;
        if (k1 >= 0) s_cols[r][k1] = f[j].y;
        if (k2 >= 0) s_cols[r][k2] = f[j].z;
        if (k3 >= 0) s_cols[r][k3] = f[j].w;
    }
    __syncthreads();

    // ---- stage 1: 16-row chunk sums ----
    {
        const int k  = tid & 15;
        const int cA = tid >> 4;                   // 0..31
        float s = 0.0f;
        #pragma unroll
        for (int i = 0; i < 16; ++i) s += s_cols[cA * 16 + i][k];
        s_ps[cA][k] = s;
        if (cA < NCHUNK - 32) {                    // chunks 32..39
            const int cB = cA + 32;
            float s2 = 0.0f;
            #pragma unroll
            for (int i = 0; i < 16; ++i) s2 += s_cols[cB * 16 + i][k];
            s_ps[cB][k] = s2;
        }
    }
    __syncthreads();

    // ---- stage 2: warmup from 8 chunk sums, then 16-step slide ----
    float means[RPT];
    const int k   = tid & 15;
    const int sub = tid >> 4;                      // 0..31
    {
        float S = 0.0f;
        #pragma unroll
        for (int m = 0; m < 8; ++m) S += s_ps[sub + m][k];
        const float inv = 1.0f / (float)WINDOW;
        #pragma unroll
        for (int i = 0; i < RPT; ++i) {
            means[i] = S * inv;
            // window advances: +row(t), -row(t-128)
            S += s_cols[HALO + sub * RPT + i][k] - s_cols[sub * RPT + i][k];
        }
    }
    __syncthreads();
    #pragma unroll
    for (int i = 0; i < RPT; ++i)
        s_cols[HALO + sub * RPT + i][k] = means[i]; // means in place
    __syncthreads();

    // ---- substitution + coalesced store from registers ----
    float4* __restrict__ out4 = reinterpret_cast<float4*>(out);
    if (!first) {
        #pragma unroll
        for (int j = 0; j < 16; ++j) {
            const int r = rb + j * 32;
            if (k0 >= 0) f[j].x = s_cols[HALO + r][k0];
            if (k1 >= 0) f[j].y = s_cols[HALO + r][k1];
            if (k2 >= 0) f[j].z = s_cols[HALO + r][k2];
            if (k3 >= 0) f[j].w = s_cols[HALO + r][k3];
            out4[base + tid + j * NTHR] = f[j];
        }
    } else {
        #pragma unroll
        for (int j = 0; j < 16; ++j) {
            const int r = rb + j * 32;
            if (j >= 4) {                          // r >= 128 iff j >= 4
                if (k0 >= 0) f[j].x = s_cols[HALO + r][k0];
                if (k1 >= 0) f[j].y = s_cols[HALO + r][k1];
                if (k2 >= 0) f[j].z = s_cols[HALO + r][k2];
                if (k3 >= 0) f[j].w = s_cols[HALO + r][k3];
            }
            out4[base + tid + j * NTHR] = f[j];
        }
    }
}

extern "C" void kernel_launch(void* const* d_in, const int* in_sizes, int n_in,
                              void* d_out, int out_size, void* d_ws, size_t ws_size,
                              hipStream_t stream) {
    const float* inp   = (const float*)d_in[0];
    const int*   feats = (const int*)d_in[1];
    float*       out   = (float*)d_out;

    dim3 grid(T_ROWS / C_ROWS);   // 2048 blocks
    dim3 block(NTHR);
    hipLaunchKernelGGL(ma_single_read_kernel, grid, block, 0, stream,
                       inp, feats, out);
}

// Round 4
// 81.952 us; speedup vs baseline: 3.4756x; 1.3219x over previous
//
#include <hip/hip_runtime.h>

#define T_ROWS    1048576
#define F_COLS    64
#define K_FEATS   16
#define WINDOW    128
#define C_ROWS    512
#define NTHR      512
#define F4        16                  // float4 per row
#define HALO      128
#define TOT_ROWS  (C_ROWS + HALO)     // 640
#define SPAD      17                  // padded leading dim for s_cols
#define NCHUNK    (TOT_ROWS / 16)     // 40 chunks of 16 rows
#define NSUB      32                  // row sub-groups in phase A
#define RPT       (C_ROWS / NSUB)     // 16 rows per phase-A thread
#define NBLK      (T_ROWS / C_ROWS)   // 2048
#define NXCD      8
#define CPX       (NBLK / NXCD)       // 256 blocks per XCD chunk

typedef float f32x4 __attribute__((ext_vector_type(4)));

__global__ __launch_bounds__(NTHR, 4) void ma_single_read_kernel(
    const float* __restrict__ inp,
    const int*   __restrict__ feats,
    float*       __restrict__ out)
{
    __shared__ float s_cols[TOT_ROWS][SPAD];   // 43.5 KB
    __shared__ float s_ps[NCHUNK][K_FEATS];    // 2.5 KB

    const int tid = threadIdx.x;

    // T1: XCD-aware bijective swizzle (2048 % 8 == 0). Default dispatch
    // round-robins XCDs (bid%8 = XCD); remap so logically-consecutive row
    // chunks share an XCD -> halo reads hit that XCD's L2.
    const int bid     = blockIdx.x;
    const int logical = (bid & (NXCD - 1)) * CPX + (bid >> 3);
    const int r0      = logical * C_ROWS;
    const bool first  = (logical == 0);

    const float4* __restrict__ in4 = reinterpret_cast<const float4*>(inp);
    const long base = (long)r0 * F4;

    // ---- issue ALL global loads first (20 x 16B per thread in flight) ----
    float4 f[16];                                  // block's own 512 rows
    #pragma unroll
    for (int j = 0; j < 16; ++j)
        f[j] = in4[base + tid + j * NTHR];

    float4 h[4];                                   // 128 halo rows
    if (!first) {
        const long hbase = (long)(r0 - HALO) * F4;
        #pragma unroll
        for (int m = 0; m < 4; ++m)
            h[m] = in4[hbase + tid + m * NTHR];
    }

    // ---- per-thread feat mapping: this thread always owns cols c0..c0+3 ----
    const int c0 = (tid & 15) * 4;
    int k0 = -1, k1 = -1, k2 = -1, k3 = -1;
    #pragma unroll
    for (int i = 0; i < K_FEATS; ++i) {
        const int c = feats[i];                    // uniform -> scalar loads
        if (c == c0 + 0) k0 = i;
        if (c == c0 + 1) k1 = i;
        if (c == c0 + 2) k2 = i;
        if (c == c0 + 3) k3 = i;
    }
    const int rb = tid >> 4;                       // row-base 0..31

    // ---- extraction: scatter feat columns into s_cols ----
    if (!first) {
        #pragma unroll
        for (int m = 0; m < 4; ++m) {
            const int r = rb + m * 32;             // halo rows 0..127
            if (k0 >= 0) s_cols[r][k0] = h[m].x;
            if (k1 >= 0) s_cols[r][k1] = h[m].y;
            if (k2 >= 0) s_cols[r][k2] = h[m].z;
            if (k3 >= 0) s_cols[r][k3] = h[m].w;
        }
    } else {
        if (tid < HALO) {
            #pragma unroll
            for (int k = 0; k < K_FEATS; ++k) s_cols[tid][k] = 0.0f;
        }
    }
    #pragma unroll
    for (int j = 0; j < 16; ++j) {
        const int r = HALO + rb + j * 32;          // own rows 128..639
        if (k0 >= 0) s_cols[r][k0] = f[j].x;
        if (k1 >= 0) s_cols[r][k1] = f[j].y;
        if (k2 >= 0) s_cols[r][k2] = f[j].z;
        if (k3 >= 0) s_cols[r][k3] = f[j].w;
    }
    __syncthreads();

    // ---- stage 1: 16-row chunk sums ----
    {
        const int k  = tid & 15;
        const int cA = tid >> 4;                   // 0..31
        float s = 0.0f;
        #pragma unroll
        for (int i = 0; i < 16; ++i) s += s_cols[cA * 16 + i][k];
        s_ps[cA][k] = s;
        if (cA < NCHUNK - 32) {                    // chunks 32..39
            const int cB = cA + 32;
            float s2 = 0.0f;
            #pragma unroll
            for (int i = 0; i < 16; ++i) s2 += s_cols[cB * 16 + i][k];
            s_ps[cB][k] = s2;
        }
    }
    __syncthreads();

    // ---- stage 2: warmup from 8 chunk sums, then 16-step slide ----
    float means[RPT];
    const int k   = tid & 15;
    const int sub = tid >> 4;                      // 0..31
    {
        float S = 0.0f;
        #pragma unroll
        for (int m = 0; m < 8; ++m) S += s_ps[sub + m][k];
        const float inv = 1.0f / (float)WINDOW;
        #pragma unroll
        for (int i = 0; i < RPT; ++i) {
            means[i] = S * inv;
            S += s_cols[HALO + sub * RPT + i][k] - s_cols[sub * RPT + i][k];
        }
    }
    __syncthreads();
    #pragma unroll
    for (int i = 0; i < RPT; ++i)
        s_cols[HALO + sub * RPT + i][k] = means[i]; // means in place
    __syncthreads();

    // ---- substitution + coalesced NT store from registers ----
    f32x4* __restrict__ out4 = reinterpret_cast<f32x4*>(out);
    if (!first) {
        #pragma unroll
        for (int j = 0; j < 16; ++j) {
            const int r = rb + j * 32;
            if (k0 >= 0) f[j].x = s_cols[HALO + r][k0];
            if (k1 >= 0) f[j].y = s_cols[HALO + r][k1];
            if (k2 >= 0) f[j].z = s_cols[HALO + r][k2];
            if (k3 >= 0) f[j].w = s_cols[HALO + r][k3];
            f32x4 v = { f[j].x, f[j].y, f[j].z, f[j].w };
            __builtin_nontemporal_store(v, &out4[base + tid + j * NTHR]);
        }
    } else {
        #pragma unroll
        for (int j = 0; j < 16; ++j) {
            const int r = rb + j * 32;
            if (j >= 4) {                          // r >= 128 iff j >= 4
                if (k0 >= 0) f[j].x = s_cols[HALO + r][k0];
                if (k1 >= 0) f[j].y = s_cols[HALO + r][k1];
                if (k2 >= 0) f[j].z = s_cols[HALO + r][k2];
                if (k3 >= 0) f[j].w = s_cols[HALO + r][k3];
            }
            f32x4 v = { f[j].x, f[j].y, f[j].z, f[j].w };
            __builtin_nontemporal_store(v, &out4[base + tid + j * NTHR]);
        }
    }
}

extern "C" void kernel_launch(void* const* d_in, const int* in_sizes, int n_in,
                              void* d_out, int out_size, void* d_ws, size_t ws_size,
                              hipStream_t stream) {
    const float* inp   = (const float*)d_in[0];
    const int*   feats = (const int*)d_in[1];
    float*       out   = (float*)d_out;

    dim3 grid(NBLK);   // 2048 blocks
    dim3 block(NTHR);
    hipLaunchKernelGGL(ma_single_read_kernel, grid, block, 0, stream,
                       inp, feats, out);
}